// Round 5
// baseline (565.686 us; speedup 1.0000x reference)
//
#include <hip/hip_runtime.h>

#define IN_DIM 128
#define HID 128
#define SRC_BITS 17            // N=100000 < 2^17
#define SRC_MASK 0x1FFFF

typedef __attribute__((ext_vector_type(8))) short short8;
typedef __attribute__((ext_vector_type(4))) float f32x4;

__device__ __forceinline__ unsigned short f2bf(float f) {
    union { float f; unsigned u; } a; a.f = f;
    unsigned r = a.u + 0x7fffu + ((a.u >> 16) & 1u);
    return (unsigned short)(r >> 16);
}

// ---------- coarse histogram: bucket = dst >> 7 ----------
__global__ __launch_bounds__(256) void hist_kernel(const int* __restrict__ dst,
                                                   int* __restrict__ bhist, int E, int nbuk) {
    __shared__ int sh[1024];
    const int tid = threadIdx.x;
    for (int i = tid; i < 1024; i += 256) sh[i] = 0;
    __syncthreads();
    for (int e = blockIdx.x * 256 + tid; e < E; e += gridDim.x * 256)
        atomicAdd(&sh[dst[e] >> 7], 1);
    __syncthreads();
    for (int i = tid; i < nbuk; i += 256) {
        int v = sh[i];
        if (v) atomicAdd(&bhist[i], v);
    }
}

// ---------- exclusive scan of bucket counts (single block, <=1024 buckets) ----------
__global__ __launch_bounds__(256) void bscan_kernel(const int* __restrict__ bhist,
                                                    int* __restrict__ boff,
                                                    int* __restrict__ bcur, int nbuk, int E) {
    __shared__ int sh[256];
    const int tid = threadIdx.x;
    const int base = tid * 4;
    int v[4];
#pragma unroll
    for (int j = 0; j < 4; ++j) { int i = base + j; v[j] = (i < nbuk) ? bhist[i] : 0; }
    int sum = v[0] + v[1] + v[2] + v[3];
    sh[tid] = sum;
    __syncthreads();
    for (int off = 1; off < 256; off <<= 1) {
        int t = (tid >= off) ? sh[tid - off] : 0;
        __syncthreads();
        sh[tid] += t;
        __syncthreads();
    }
    int run = sh[tid] - sum;
#pragma unroll
    for (int j = 0; j < 4; ++j) {
        int i = base + j;
        if (i < nbuk) { boff[i] = run; bcur[i] = run; }
        run += v[j];
    }
    if (tid == 255) boff[nbuk] = E;
}

// ---------- scatter packed (dstLow | src) into coarse buckets ----------
__global__ __launch_bounds__(256) void scatterB_kernel(const int* __restrict__ src,
                                                       const int* __restrict__ dst,
                                                       int* __restrict__ bcur,
                                                       int* __restrict__ packed, int E) {
    int e = blockIdx.x * 256 + threadIdx.x;
    if (e < E) {
        int d = dst[e];
        int pos = atomicAdd(&bcur[d >> 7], 1);
        packed[pos] = ((d & 127) << SRC_BITS) | src[e];
    }
}

// ---------- per-bucket: exact CSR build + deg/norm (one block per bucket) ----------
__global__ __launch_bounds__(256) void buildC_kernel(const int* __restrict__ packed,
                                                     const int* __restrict__ boff,
                                                     int* __restrict__ sorted_src,
                                                     int* __restrict__ rowptr,
                                                     float* __restrict__ norm, int n) {
    __shared__ int cnt[128], tmp[128], cur[128];
    const int tid = threadIdx.x;
    const int b = blockIdx.x;
    const int base = boff[b];
    const int ecnt = boff[b + 1] - base;
    const int node0 = b << 7;

    if (tid < 128) cnt[tid] = 0;
    __syncthreads();
    for (int i = tid; i < ecnt; i += 256)
        atomicAdd(&cnt[packed[base + i] >> SRC_BITS], 1);
    __syncthreads();

    int v = 0;
    if (tid < 128) { v = cnt[tid]; tmp[tid] = v; }
    __syncthreads();
    for (int off = 1; off < 128; off <<= 1) {
        int t = 0;
        if (tid < 128 && tid >= off) t = tmp[tid - off];
        __syncthreads();
        if (tid < 128) tmp[tid] += t;
        __syncthreads();
    }
    if (tid < 128) {
        int excl = tmp[tid] - v;
        cur[tid] = excl;
        int node = node0 + tid;
        if (node < n) {
            rowptr[node] = base + excl;
            norm[node] = rsqrtf(fmaxf((float)v, 1.0f));
        }
    }
    __syncthreads();

    for (int i = tid; i < ecnt; i += 256) {
        int p = packed[base + i];
        int pos = atomicAdd(&cur[p >> SRC_BITS], 1);
        sorted_src[base + pos] = p & SRC_MASK;
    }
}

// ---------- gather-reduce: one wave per dst row ----------
__global__ __launch_bounds__(256) void agg_kernel(const float* __restrict__ h,
                                                  const float* __restrict__ norm,
                                                  const int* __restrict__ rowptr,
                                                  const int* __restrict__ sorted_src,
                                                  float* __restrict__ agg, int n, int E) {
    const int wid = (blockIdx.x * 256 + threadIdx.x) >> 6;
    const int lane = threadIdx.x & 63;
    if (wid >= n) return;
    const int start = rowptr[wid];
    const int end = (wid + 1 < n) ? rowptr[wid + 1] : E;

    float ax = 0.f, ay = 0.f;
    const float* hp = h + lane * 2;
    int k = start;
    for (; k + 7 < end; k += 8) {
        int s[8];
#pragma unroll
        for (int u = 0; u < 8; ++u) s[u] = sorted_src[k + u];
        float nn[8];
#pragma unroll
        for (int u = 0; u < 8; ++u) nn[u] = norm[s[u]];
        float2 v[8];
#pragma unroll
        for (int u = 0; u < 8; ++u) v[u] = *(const float2*)(hp + (size_t)s[u] * IN_DIM);
#pragma unroll
        for (int u = 0; u < 8; ++u) { ax += v[u].x * nn[u]; ay += v[u].y * nn[u]; }
    }
    for (; k < end; ++k) {
        int s0 = sorted_src[k];
        float n0 = norm[s0];
        float2 v0 = *(const float2*)(hp + (size_t)s0 * IN_DIM);
        ax += v0.x * n0;
        ay += v0.y * n0;
    }
    const float nd = norm[wid];
    float2 o = make_float2(ax * nd, ay * nd);
    *(float2*)(agg + (size_t)wid * IN_DIM + lane * 2) = o;
}

// ---------- pre-pack W into MFMA B-fragment lane order (bf16) ----------
__global__ __launch_bounds__(256) void packW_kernel(const float* __restrict__ W,
                                                    unsigned short* __restrict__ pw) {
    int t = blockIdx.x * 256 + threadIdx.x;  // 0..4095
    int lane = t & 63;
    int frag = t >> 6;                        // kc*8 + nt
    int kc = frag >> 3, nt = frag & 7;
    int k0 = kc * 32 + (lane >> 4) * 8;
    int col = nt * 16 + (lane & 15);
    short8 v;
#pragma unroll
    for (int j = 0; j < 8; ++j) v[j] = (short)f2bf(W[(size_t)(k0 + j) * HID + col]);
    *(short8*)(pw + (size_t)t * 8) = v;
}

// ---------- MFMA GEMM + bias + row L2-normalize ----------
__global__ __launch_bounds__(256) void gemm_kernel(const float* __restrict__ h,
                                                   const float* agg,
                                                   const unsigned short* __restrict__ pw,
                                                   const float* __restrict__ bias,
                                                   float* out, int n) {
    const int tid = threadIdx.x;
    const int wave = tid >> 6;
    const int lane = tid & 63;
    const int l15 = lane & 15;
    const int lg = lane >> 4;
    const int rowBase = blockIdx.x * 64 + wave * 16;
    const int arow = min(rowBase + l15, n - 1);

    f32x4 acc[8];
#pragma unroll
    for (int nt = 0; nt < 8; ++nt) acc[nt] = (f32x4){0.f, 0.f, 0.f, 0.f};

#pragma unroll
    for (int kc = 0; kc < 8; ++kc) {
        const int k = kc * 32 + lg * 8;
        const float* ap = (kc < 4) ? (h + (size_t)arow * IN_DIM + k)
                                   : (agg + (size_t)arow * IN_DIM + (k - 128));
        float4 a0 = *(const float4*)ap;
        float4 a1 = *(const float4*)(ap + 4);
        short8 af;
        af[0] = (short)f2bf(a0.x); af[1] = (short)f2bf(a0.y);
        af[2] = (short)f2bf(a0.z); af[3] = (short)f2bf(a0.w);
        af[4] = (short)f2bf(a1.x); af[5] = (short)f2bf(a1.y);
        af[6] = (short)f2bf(a1.z); af[7] = (short)f2bf(a1.w);
        const unsigned short* bp = pw + ((size_t)(kc * 8) * 64 + lane) * 8;
#pragma unroll
        for (int nt = 0; nt < 8; ++nt) {
            short8 bf = *(const short8*)(bp + (size_t)nt * 64 * 8);
            acc[nt] = __builtin_amdgcn_mfma_f32_16x16x32_bf16(af, bf, acc[nt], 0, 0, 0);
        }
    }

    float ss[4] = {0.f, 0.f, 0.f, 0.f};
#pragma unroll
    for (int nt = 0; nt < 8; ++nt) {
        float b = bias[nt * 16 + l15];
#pragma unroll
        for (int j = 0; j < 4; ++j) {
            float y = acc[nt][j] + b;
            acc[nt][j] = y;
            ss[j] += y * y;
        }
    }
#pragma unroll
    for (int m = 1; m < 16; m <<= 1) {
#pragma unroll
        for (int j = 0; j < 4; ++j) ss[j] += __shfl_xor(ss[j], m);
    }
#pragma unroll
    for (int j = 0; j < 4; ++j) {
        const int r = rowBase + lg * 4 + j;
        if (r < n) {
            const float inv = rsqrtf(ss[j]);
            float* op = out + (size_t)r * HID + l15;
#pragma unroll
            for (int nt = 0; nt < 8; ++nt) op[nt * 16] = acc[nt][j] * inv;
        }
    }
}

extern "C" void kernel_launch(void* const* d_in, const int* in_sizes, int n_in,
                              void* d_out, int out_size, void* d_ws, size_t ws_size,
                              hipStream_t stream) {
    const float* h = (const float*)d_in[0];
    const float* W = (const float*)d_in[1];
    const float* bias = (const float*)d_in[2];
    const int* src = (const int*)d_in[3];
    const int* dst = (const int*)d_in[4];
    float* out = (float*)d_out;

    const int n = in_sizes[0] / IN_DIM;   // 100000
    const int E = in_sizes[3];            // 1600000
    const int nbuk = (n + 127) / 128;     // 782

    // ws: rowptr[N] | norm[N] | bhist[1024] | boff[1025+pad] | bcur[1024] | sorted_src[E] | pw
    int* rowptr = (int*)d_ws;
    float* norm = (float*)(rowptr + n);
    int* bhist = (int*)(norm + n);
    int* boff = bhist + 1024;
    int* bcur = boff + 1026;
    int* sorted_src = bcur + 1024;
    unsigned short* pw = (unsigned short*)(sorted_src + E);

    // packed edges live in the tail of d_out; fully consumed by buildC before
    // agg overwrites d_out, and fully rewritten every call (replay-safe).
    int* packed = (int*)d_out + (out_size - E);

    hipMemsetAsync(bhist, 0, 1024 * sizeof(int), stream);

    packW_kernel<<<16, 256, 0, stream>>>(W, pw);
    hist_kernel<<<256, 256, 0, stream>>>(dst, bhist, E, nbuk);
    bscan_kernel<<<1, 256, 0, stream>>>(bhist, boff, bcur, nbuk, E);
    scatterB_kernel<<<(E + 255) / 256, 256, 0, stream>>>(src, dst, bcur, packed, E);
    buildC_kernel<<<nbuk, 256, 0, stream>>>(packed, boff, sorted_src, rowptr, norm, n);

    agg_kernel<<<(n + 3) / 4, 256, 0, stream>>>(h, norm, rowptr, sorted_src, out, n, E);

    gemm_kernel<<<(n + 63) / 64, 256, 0, stream>>>(h, out, pw, bias, out, n);
}

// Round 6
// 220.784 us; speedup vs baseline: 2.5622x; 2.5622x over previous
//
#include <hip/hip_runtime.h>

#define IN_DIM 128
#define HID 128
#define SRC_BITS 17            // N=100000 < 2^17
#define SRC_MASK 0x1FFFF

typedef __attribute__((ext_vector_type(8))) short short8;
typedef __attribute__((ext_vector_type(4))) float f32x4;

__device__ __forceinline__ unsigned short f2bf(float f) {
    union { float f; unsigned u; } a; a.f = f;
    unsigned r = a.u + 0x7fffu + ((a.u >> 16) & 1u);
    return (unsigned short)(r >> 16);
}

// ---------- coarse histogram: bucket = dst >> 7 ----------
__global__ __launch_bounds__(256) void hist_kernel(const int* __restrict__ dst,
                                                   int* __restrict__ bhist, int E, int nbuk) {
    __shared__ int sh[1024];
    const int tid = threadIdx.x;
    for (int i = tid; i < 1024; i += 256) sh[i] = 0;
    __syncthreads();
    for (int e = blockIdx.x * 256 + tid; e < E; e += gridDim.x * 256)
        atomicAdd(&sh[dst[e] >> 7], 1);
    __syncthreads();
    for (int i = tid; i < nbuk; i += 256) {
        int v = sh[i];
        if (v) atomicAdd(&bhist[i], v);
    }
}

// ---------- exclusive scan of bucket counts (single block, <=1024 buckets) ----------
__global__ __launch_bounds__(256) void bscan_kernel(const int* __restrict__ bhist,
                                                    int* __restrict__ boff,
                                                    int* __restrict__ bcur, int nbuk, int E) {
    __shared__ int sh[256];
    const int tid = threadIdx.x;
    const int base = tid * 4;
    int v[4];
#pragma unroll
    for (int j = 0; j < 4; ++j) { int i = base + j; v[j] = (i < nbuk) ? bhist[i] : 0; }
    int sum = v[0] + v[1] + v[2] + v[3];
    sh[tid] = sum;
    __syncthreads();
    for (int off = 1; off < 256; off <<= 1) {
        int t = (tid >= off) ? sh[tid - off] : 0;
        __syncthreads();
        sh[tid] += t;
        __syncthreads();
    }
    int run = sh[tid] - sum;
#pragma unroll
    for (int j = 0; j < 4; ++j) {
        int i = base + j;
        if (i < nbuk) { boff[i] = run; bcur[i] = run; }
        run += v[j];
    }
    if (tid == 255) boff[nbuk] = E;
}

// ---------- block-aggregated scatter into coarse buckets ----------
// Each block: LDS-histogram its chunk, ONE global atomicAdd per non-empty
// bucket to reserve a contiguous range, then place edges via LDS atomics.
__global__ __launch_bounds__(256) void scatterB_kernel(const int* __restrict__ src,
                                                       const int* __restrict__ dst,
                                                       int* __restrict__ bcur,
                                                       int* __restrict__ packed,
                                                       int E, int chunk) {
    __shared__ int cnt[1024];
    __shared__ int base[1024];
    const int tid = threadIdx.x;
    const int e0 = blockIdx.x * chunk;
    const int e1 = min(E, e0 + chunk);
    for (int i = tid; i < 1024; i += 256) cnt[i] = 0;
    __syncthreads();
    for (int e = e0 + tid; e < e1; e += 256)
        atomicAdd(&cnt[dst[e] >> 7], 1);
    __syncthreads();
    for (int i = tid; i < 1024; i += 256) {
        int c = cnt[i];
        base[i] = (c > 0) ? atomicAdd(&bcur[i], c) : 0;
        cnt[i] = 0;
    }
    __syncthreads();
    for (int e = e0 + tid; e < e1; e += 256) {
        int d = dst[e];
        int b = d >> 7;
        int local = atomicAdd(&cnt[b], 1);
        packed[base[b] + local] = ((d & 127) << SRC_BITS) | src[e];
    }
}

// ---------- per-bucket: exact CSR build + deg/norm (one block per bucket) ----------
__global__ __launch_bounds__(256) void buildC_kernel(const int* __restrict__ packed,
                                                     const int* __restrict__ boff,
                                                     int* __restrict__ sorted_src,
                                                     int* __restrict__ rowptr,
                                                     float* __restrict__ norm, int n) {
    __shared__ int cnt[128], tmp[128], cur[128];
    const int tid = threadIdx.x;
    const int b = blockIdx.x;
    const int base = boff[b];
    const int ecnt = boff[b + 1] - base;
    const int node0 = b << 7;

    if (tid < 128) cnt[tid] = 0;
    __syncthreads();
    for (int i = tid; i < ecnt; i += 256)
        atomicAdd(&cnt[packed[base + i] >> SRC_BITS], 1);
    __syncthreads();

    int v = 0;
    if (tid < 128) { v = cnt[tid]; tmp[tid] = v; }
    __syncthreads();
    for (int off = 1; off < 128; off <<= 1) {
        int t = 0;
        if (tid < 128 && tid >= off) t = tmp[tid - off];
        __syncthreads();
        if (tid < 128) tmp[tid] += t;
        __syncthreads();
    }
    if (tid < 128) {
        int excl = tmp[tid] - v;
        cur[tid] = excl;
        int node = node0 + tid;
        if (node < n) {
            rowptr[node] = base + excl;
            norm[node] = rsqrtf(fmaxf((float)v, 1.0f));
        }
    }
    __syncthreads();

    for (int i = tid; i < ecnt; i += 256) {
        int p = packed[base + i];
        int pos = atomicAdd(&cur[p >> SRC_BITS], 1);
        sorted_src[base + pos] = p & SRC_MASK;
    }
}

// ---------- gather-reduce: one wave per dst row ----------
__global__ __launch_bounds__(256) void agg_kernel(const float* __restrict__ h,
                                                  const float* __restrict__ norm,
                                                  const int* __restrict__ rowptr,
                                                  const int* __restrict__ sorted_src,
                                                  float* __restrict__ agg, int n, int E) {
    const int wid = (blockIdx.x * 256 + threadIdx.x) >> 6;
    const int lane = threadIdx.x & 63;
    if (wid >= n) return;
    const int start = rowptr[wid];
    const int end = (wid + 1 < n) ? rowptr[wid + 1] : E;

    float ax = 0.f, ay = 0.f;
    const float* hp = h + lane * 2;
    int k = start;
    for (; k + 7 < end; k += 8) {
        int s[8];
#pragma unroll
        for (int u = 0; u < 8; ++u) s[u] = sorted_src[k + u];
        float nn[8];
#pragma unroll
        for (int u = 0; u < 8; ++u) nn[u] = norm[s[u]];
        float2 v[8];
#pragma unroll
        for (int u = 0; u < 8; ++u) v[u] = *(const float2*)(hp + (size_t)s[u] * IN_DIM);
#pragma unroll
        for (int u = 0; u < 8; ++u) { ax += v[u].x * nn[u]; ay += v[u].y * nn[u]; }
    }
    for (; k < end; ++k) {
        int s0 = sorted_src[k];
        float n0 = norm[s0];
        float2 v0 = *(const float2*)(hp + (size_t)s0 * IN_DIM);
        ax += v0.x * n0;
        ay += v0.y * n0;
    }
    const float nd = norm[wid];
    float2 o = make_float2(ax * nd, ay * nd);
    *(float2*)(agg + (size_t)wid * IN_DIM + lane * 2) = o;
}

// ---------- pre-pack W into MFMA B-fragment lane order (bf16) ----------
__global__ __launch_bounds__(256) void packW_kernel(const float* __restrict__ W,
                                                    unsigned short* __restrict__ pw) {
    int t = blockIdx.x * 256 + threadIdx.x;  // 0..4095
    int lane = t & 63;
    int frag = t >> 6;                        // kc*8 + nt
    int kc = frag >> 3, nt = frag & 7;
    int k0 = kc * 32 + (lane >> 4) * 8;
    int col = nt * 16 + (lane & 15);
    short8 v;
#pragma unroll
    for (int j = 0; j < 8; ++j) v[j] = (short)f2bf(W[(size_t)(k0 + j) * HID + col]);
    *(short8*)(pw + (size_t)t * 8) = v;
}

// ---------- MFMA GEMM + bias + row L2-normalize ----------
__global__ __launch_bounds__(256) void gemm_kernel(const float* __restrict__ h,
                                                   const float* agg,
                                                   const unsigned short* __restrict__ pw,
                                                   const float* __restrict__ bias,
                                                   float* out, int n) {
    const int tid = threadIdx.x;
    const int wave = tid >> 6;
    const int lane = tid & 63;
    const int l15 = lane & 15;
    const int lg = lane >> 4;
    const int rowBase = blockIdx.x * 64 + wave * 16;
    const int arow = min(rowBase + l15, n - 1);

    f32x4 acc[8];
#pragma unroll
    for (int nt = 0; nt < 8; ++nt) acc[nt] = (f32x4){0.f, 0.f, 0.f, 0.f};

#pragma unroll
    for (int kc = 0; kc < 8; ++kc) {
        const int k = kc * 32 + lg * 8;
        const float* ap = (kc < 4) ? (h + (size_t)arow * IN_DIM + k)
                                   : (agg + (size_t)arow * IN_DIM + (k - 128));
        float4 a0 = *(const float4*)ap;
        float4 a1 = *(const float4*)(ap + 4);
        short8 af;
        af[0] = (short)f2bf(a0.x); af[1] = (short)f2bf(a0.y);
        af[2] = (short)f2bf(a0.z); af[3] = (short)f2bf(a0.w);
        af[4] = (short)f2bf(a1.x); af[5] = (short)f2bf(a1.y);
        af[6] = (short)f2bf(a1.z); af[7] = (short)f2bf(a1.w);
        const unsigned short* bp = pw + ((size_t)(kc * 8) * 64 + lane) * 8;
#pragma unroll
        for (int nt = 0; nt < 8; ++nt) {
            short8 bf = *(const short8*)(bp + (size_t)nt * 64 * 8);
            acc[nt] = __builtin_amdgcn_mfma_f32_16x16x32_bf16(af, bf, acc[nt], 0, 0, 0);
        }
    }

    float ss[4] = {0.f, 0.f, 0.f, 0.f};
#pragma unroll
    for (int nt = 0; nt < 8; ++nt) {
        float b = bias[nt * 16 + l15];
#pragma unroll
        for (int j = 0; j < 4; ++j) {
            float y = acc[nt][j] + b;
            acc[nt][j] = y;
            ss[j] += y * y;
        }
    }
#pragma unroll
    for (int m = 1; m < 16; m <<= 1) {
#pragma unroll
        for (int j = 0; j < 4; ++j) ss[j] += __shfl_xor(ss[j], m);
    }
#pragma unroll
    for (int j = 0; j < 4; ++j) {
        const int r = rowBase + lg * 4 + j;
        if (r < n) {
            const float inv = rsqrtf(ss[j]);
            float* op = out + (size_t)r * HID + l15;
#pragma unroll
            for (int nt = 0; nt < 8; ++nt) op[nt * 16] = acc[nt][j] * inv;
        }
    }
}

extern "C" void kernel_launch(void* const* d_in, const int* in_sizes, int n_in,
                              void* d_out, int out_size, void* d_ws, size_t ws_size,
                              hipStream_t stream) {
    const float* h = (const float*)d_in[0];
    const float* W = (const float*)d_in[1];
    const float* bias = (const float*)d_in[2];
    const int* src = (const int*)d_in[3];
    const int* dst = (const int*)d_in[4];
    float* out = (float*)d_out;

    const int n = in_sizes[0] / IN_DIM;   // 100000
    const int E = in_sizes[3];            // 1600000
    const int nbuk = (n + 127) / 128;     // 782

    // ws: rowptr[N] | norm[N] | bhist[1024] | boff[1026] | bcur[1024] | sorted_src[E] | pw
    int* rowptr = (int*)d_ws;
    float* norm = (float*)(rowptr + n);
    int* bhist = (int*)(norm + n);
    int* boff = bhist + 1024;
    int* bcur = boff + 1026;
    int* sorted_src = bcur + 1024;
    unsigned short* pw = (unsigned short*)(sorted_src + E);

    // packed edges live in the tail of d_out; fully consumed by buildC before
    // agg overwrites d_out, and fully rewritten every call (replay-safe).
    int* packed = (int*)d_out + (out_size - E);

    hipMemsetAsync(bhist, 0, 1024 * sizeof(int), stream);

    packW_kernel<<<16, 256, 0, stream>>>(W, pw);
    hist_kernel<<<256, 256, 0, stream>>>(dst, bhist, E, nbuk);
    bscan_kernel<<<1, 256, 0, stream>>>(bhist, boff, bcur, nbuk, E);

    const int NB = 256;
    const int chunk = (E + NB - 1) / NB;  // 6250
    scatterB_kernel<<<NB, 256, 0, stream>>>(src, dst, bcur, packed, E, chunk);

    buildC_kernel<<<nbuk, 256, 0, stream>>>(packed, boff, sorted_src, rowptr, norm, n);

    agg_kernel<<<(n + 3) / 4, 256, 0, stream>>>(h, norm, rowptr, sorted_src, out, n, E);

    gemm_kernel<<<(n + 63) / 64, 256, 0, stream>>>(h, out, pw, bias, out, n);
}

// Round 7
// 201.594 us; speedup vs baseline: 2.8061x; 1.0952x over previous
//
#include <hip/hip_runtime.h>

#define IN_DIM 128
#define HID 128
#define SRC_BITS 17            // N=100000 < 2^17
#define SRC_MASK 0x1FFFF

typedef __attribute__((ext_vector_type(8))) short short8;
typedef __attribute__((ext_vector_type(4))) float f32x4;

__device__ __forceinline__ unsigned short f2bf(float f) {
    union { float f; unsigned u; } a; a.f = f;
    unsigned r = a.u + 0x7fffu + ((a.u >> 16) & 1u);
    return (unsigned short)(r >> 16);
}

// ---------- h -> bf16 copy ----------
__global__ __launch_bounds__(256) void prep_kernel(const float* __restrict__ h,
                                                   unsigned short* __restrict__ hb, int total8) {
    int i = blockIdx.x * 256 + threadIdx.x;
    if (i >= total8) return;
    const float4 a0 = *(const float4*)(h + (size_t)i * 8);
    const float4 a1 = *(const float4*)(h + (size_t)i * 8 + 4);
    short8 v;
    v[0] = (short)f2bf(a0.x); v[1] = (short)f2bf(a0.y);
    v[2] = (short)f2bf(a0.z); v[3] = (short)f2bf(a0.w);
    v[4] = (short)f2bf(a1.x); v[5] = (short)f2bf(a1.y);
    v[6] = (short)f2bf(a1.z); v[7] = (short)f2bf(a1.w);
    *(short8*)(hb + (size_t)i * 8) = v;
}

// ---------- coarse histogram: bucket = dst >> 7 ----------
__global__ __launch_bounds__(256) void hist_kernel(const int* __restrict__ dst,
                                                   int* __restrict__ bhist, int E, int nbuk) {
    __shared__ int sh[1024];
    const int tid = threadIdx.x;
    for (int i = tid; i < 1024; i += 256) sh[i] = 0;
    __syncthreads();
    for (int e = blockIdx.x * 256 + tid; e < E; e += gridDim.x * 256)
        atomicAdd(&sh[dst[e] >> 7], 1);
    __syncthreads();
    for (int i = tid; i < nbuk; i += 256) {
        int v = sh[i];
        if (v) atomicAdd(&bhist[i], v);
    }
}

// ---------- exclusive scan of bucket counts ----------
__global__ __launch_bounds__(256) void bscan_kernel(const int* __restrict__ bhist,
                                                    int* __restrict__ boff,
                                                    int* __restrict__ bcur, int nbuk, int E) {
    __shared__ int sh[256];
    const int tid = threadIdx.x;
    const int base = tid * 4;
    int v[4];
#pragma unroll
    for (int j = 0; j < 4; ++j) { int i = base + j; v[j] = (i < nbuk) ? bhist[i] : 0; }
    int sum = v[0] + v[1] + v[2] + v[3];
    sh[tid] = sum;
    __syncthreads();
    for (int off = 1; off < 256; off <<= 1) {
        int t = (tid >= off) ? sh[tid - off] : 0;
        __syncthreads();
        sh[tid] += t;
        __syncthreads();
    }
    int run = sh[tid] - sum;
#pragma unroll
    for (int j = 0; j < 4; ++j) {
        int i = base + j;
        if (i < nbuk) { boff[i] = run; bcur[i] = run; }
        run += v[j];
    }
    if (tid == 255) boff[nbuk] = E;
}

// ---------- block-aggregated scatter into coarse buckets ----------
__global__ __launch_bounds__(256) void scatterB_kernel(const int* __restrict__ src,
                                                       const int* __restrict__ dst,
                                                       int* __restrict__ bcur,
                                                       int* __restrict__ packed,
                                                       int E, int chunk) {
    __shared__ int cnt[1024];
    __shared__ int base[1024];
    const int tid = threadIdx.x;
    const int e0 = blockIdx.x * chunk;
    const int e1 = min(E, e0 + chunk);
    for (int i = tid; i < 1024; i += 256) cnt[i] = 0;
    __syncthreads();
    for (int e = e0 + tid; e < e1; e += 256)
        atomicAdd(&cnt[dst[e] >> 7], 1);
    __syncthreads();
    for (int i = tid; i < 1024; i += 256) {
        int c = cnt[i];
        base[i] = (c > 0) ? atomicAdd(&bcur[i], c) : 0;
        cnt[i] = 0;
    }
    __syncthreads();
    for (int e = e0 + tid; e < e1; e += 256) {
        int d = dst[e];
        int b = d >> 7;
        int local = atomicAdd(&cnt[b], 1);
        packed[base[b] + local] = ((d & 127) << SRC_BITS) | src[e];
    }
}

// ---------- per-bucket exact CSR build + deg/norm ----------
__global__ __launch_bounds__(256) void buildC_kernel(const int* __restrict__ packed,
                                                     const int* __restrict__ boff,
                                                     int* __restrict__ sorted_src,
                                                     int* __restrict__ rowptr,
                                                     float* __restrict__ norm, int n) {
    __shared__ int cnt[128], tmp[128], cur[128];
    const int tid = threadIdx.x;
    const int b = blockIdx.x;
    const int base = boff[b];
    const int ecnt = boff[b + 1] - base;
    const int node0 = b << 7;

    if (tid < 128) cnt[tid] = 0;
    __syncthreads();
    for (int i = tid; i < ecnt; i += 256)
        atomicAdd(&cnt[packed[base + i] >> SRC_BITS], 1);
    __syncthreads();

    int v = 0;
    if (tid < 128) { v = cnt[tid]; tmp[tid] = v; }
    __syncthreads();
    for (int off = 1; off < 128; off <<= 1) {
        int t = 0;
        if (tid < 128 && tid >= off) t = tmp[tid - off];
        __syncthreads();
        if (tid < 128) tmp[tid] += t;
        __syncthreads();
    }
    if (tid < 128) {
        int excl = tmp[tid] - v;
        cur[tid] = excl;
        int node = node0 + tid;
        if (node < n) {
            rowptr[node] = base + excl;
            norm[node] = rsqrtf(fmaxf((float)v, 1.0f));
        }
    }
    __syncthreads();

    for (int i = tid; i < ecnt; i += 256) {
        int p = packed[base + i];
        int pos = atomicAdd(&cur[p >> SRC_BITS], 1);
        sorted_src[base + pos] = p & SRC_MASK;
    }
}

// ---------- gather-reduce: one wave per dst row ----------
__global__ __launch_bounds__(256) void agg_kernel(const float* __restrict__ h,
                                                  const unsigned short* __restrict__ hb,
                                                  const float* __restrict__ norm,
                                                  const int* __restrict__ rowptr,
                                                  const int* __restrict__ sorted_src,
                                                  float* __restrict__ agg, int n, int E) {
    const int wid = (blockIdx.x * 256 + threadIdx.x) >> 6;
    const int lane = threadIdx.x & 63;
    if (wid >= n) return;
    const int start = rowptr[wid];
    const int end = (wid + 1 < n) ? rowptr[wid + 1] : E;

    float ax = 0.f, ay = 0.f;
    if (hb) {
        const unsigned short* hp = hb + lane * 2;
        int k = start;
        for (; k + 7 < end; k += 8) {
            int s[8];
#pragma unroll
            for (int u = 0; u < 8; ++u) s[u] = sorted_src[k + u];
            float nn[8];
#pragma unroll
            for (int u = 0; u < 8; ++u) nn[u] = norm[s[u]];
            unsigned v[8];
#pragma unroll
            for (int u = 0; u < 8; ++u) v[u] = *(const unsigned*)(hp + (size_t)s[u] * IN_DIM);
#pragma unroll
            for (int u = 0; u < 8; ++u) {
                ax += __uint_as_float(v[u] << 16) * nn[u];
                ay += __uint_as_float(v[u] & 0xffff0000u) * nn[u];
            }
        }
        for (; k < end; ++k) {
            int s0 = sorted_src[k];
            float n0 = norm[s0];
            unsigned v0 = *(const unsigned*)(hp + (size_t)s0 * IN_DIM);
            ax += __uint_as_float(v0 << 16) * n0;
            ay += __uint_as_float(v0 & 0xffff0000u) * n0;
        }
    } else {
        const float* hp = h + lane * 2;
        int k = start;
        for (; k + 7 < end; k += 8) {
            int s[8];
#pragma unroll
            for (int u = 0; u < 8; ++u) s[u] = sorted_src[k + u];
            float nn[8];
#pragma unroll
            for (int u = 0; u < 8; ++u) nn[u] = norm[s[u]];
            float2 v[8];
#pragma unroll
            for (int u = 0; u < 8; ++u) v[u] = *(const float2*)(hp + (size_t)s[u] * IN_DIM);
#pragma unroll
            for (int u = 0; u < 8; ++u) { ax += v[u].x * nn[u]; ay += v[u].y * nn[u]; }
        }
        for (; k < end; ++k) {
            int s0 = sorted_src[k];
            float n0 = norm[s0];
            float2 v0 = *(const float2*)(hp + (size_t)s0 * IN_DIM);
            ax += v0.x * n0;
            ay += v0.y * n0;
        }
    }
    const float nd = norm[wid];
    float2 o = make_float2(ax * nd, ay * nd);
    *(float2*)(agg + (size_t)wid * IN_DIM + lane * 2) = o;
}

// ---------- pre-pack W into MFMA B-fragment lane order (bf16) ----------
__global__ __launch_bounds__(256) void packW_kernel(const float* __restrict__ W,
                                                    unsigned short* __restrict__ pw) {
    int t = blockIdx.x * 256 + threadIdx.x;  // 0..4095
    int lane = t & 63;
    int frag = t >> 6;                        // kc*8 + nt
    int kc = frag >> 3, nt = frag & 7;
    int k0 = kc * 32 + (lane >> 4) * 8;
    int col = nt * 16 + (lane & 15);
    short8 v;
#pragma unroll
    for (int j = 0; j < 8; ++j) v[j] = (short)f2bf(W[(size_t)(k0 + j) * HID + col]);
    *(short8*)(pw + (size_t)t * 8) = v;
}

// ---------- MFMA GEMM + bias + row L2-normalize ----------
__global__ __launch_bounds__(256) void gemm_kernel(const float* __restrict__ h,
                                                   const unsigned short* __restrict__ hb,
                                                   const float* agg,
                                                   const unsigned short* __restrict__ pw,
                                                   const float* __restrict__ bias,
                                                   float* out, int n) {
    const int tid = threadIdx.x;
    const int wave = tid >> 6;
    const int lane = tid & 63;
    const int l15 = lane & 15;
    const int lg = lane >> 4;
    const int rowBase = blockIdx.x * 64 + wave * 16;
    const int arow = min(rowBase + l15, n - 1);

    f32x4 acc[8];
#pragma unroll
    for (int nt = 0; nt < 8; ++nt) acc[nt] = (f32x4){0.f, 0.f, 0.f, 0.f};

#pragma unroll
    for (int kc = 0; kc < 8; ++kc) {
        const int k = kc * 32 + lg * 8;
        short8 af;
        if (kc < 4) {
            if (hb) {
                af = *(const short8*)(hb + (size_t)arow * IN_DIM + k);
            } else {
                const float* ap = h + (size_t)arow * IN_DIM + k;
                float4 a0 = *(const float4*)ap;
                float4 a1 = *(const float4*)(ap + 4);
                af[0] = (short)f2bf(a0.x); af[1] = (short)f2bf(a0.y);
                af[2] = (short)f2bf(a0.z); af[3] = (short)f2bf(a0.w);
                af[4] = (short)f2bf(a1.x); af[5] = (short)f2bf(a1.y);
                af[6] = (short)f2bf(a1.z); af[7] = (short)f2bf(a1.w);
            }
        } else {
            const float* ap = agg + (size_t)arow * IN_DIM + (k - 128);
            float4 a0 = *(const float4*)ap;
            float4 a1 = *(const float4*)(ap + 4);
            af[0] = (short)f2bf(a0.x); af[1] = (short)f2bf(a0.y);
            af[2] = (short)f2bf(a0.z); af[3] = (short)f2bf(a0.w);
            af[4] = (short)f2bf(a1.x); af[5] = (short)f2bf(a1.y);
            af[6] = (short)f2bf(a1.z); af[7] = (short)f2bf(a1.w);
        }
        const unsigned short* bp = pw + ((size_t)(kc * 8) * 64 + lane) * 8;
#pragma unroll
        for (int nt = 0; nt < 8; ++nt) {
            short8 bf = *(const short8*)(bp + (size_t)nt * 64 * 8);
            acc[nt] = __builtin_amdgcn_mfma_f32_16x16x32_bf16(af, bf, acc[nt], 0, 0, 0);
        }
    }

    float ss[4] = {0.f, 0.f, 0.f, 0.f};
#pragma unroll
    for (int nt = 0; nt < 8; ++nt) {
        float b = bias[nt * 16 + l15];
#pragma unroll
        for (int j = 0; j < 4; ++j) {
            float y = acc[nt][j] + b;
            acc[nt][j] = y;
            ss[j] += y * y;
        }
    }
#pragma unroll
    for (int m = 1; m < 16; m <<= 1) {
#pragma unroll
        for (int j = 0; j < 4; ++j) ss[j] += __shfl_xor(ss[j], m);
    }
#pragma unroll
    for (int j = 0; j < 4; ++j) {
        const int r = rowBase + lg * 4 + j;
        if (r < n) {
            const float inv = rsqrtf(ss[j]);
            float* op = out + (size_t)r * HID + l15;
#pragma unroll
            for (int nt = 0; nt < 8; ++nt) op[nt * 16] = acc[nt][j] * inv;
        }
    }
}

extern "C" void kernel_launch(void* const* d_in, const int* in_sizes, int n_in,
                              void* d_out, int out_size, void* d_ws, size_t ws_size,
                              hipStream_t stream) {
    const float* h = (const float*)d_in[0];
    const float* W = (const float*)d_in[1];
    const float* bias = (const float*)d_in[2];
    const int* src = (const int*)d_in[3];
    const int* dst = (const int*)d_in[4];
    float* out = (float*)d_out;

    const int n = in_sizes[0] / IN_DIM;   // 100000
    const int E = in_sizes[3];            // 1600000
    const int nbuk = (n + 127) / 128;     // 782

    // ws: rowptr[N] | norm[N] | bhist[1024] | boff[1026] | bcur[1024] | sorted_src[E] | pw | hb
    int* rowptr = (int*)d_ws;
    float* norm = (float*)(rowptr + n);
    int* bhist = (int*)(norm + n);
    int* boff = bhist + 1024;
    int* bcur = boff + 1026;
    int* sorted_src = bcur + 1024;
    unsigned short* pw = (unsigned short*)(sorted_src + E);
    // hb after pw, 16B-aligned
    size_t hb_off = (((size_t)(pw + 4096 * 8) - (size_t)d_ws) + 15) & ~(size_t)15;
    unsigned short* hb = (unsigned short*)((char*)d_ws + hb_off);
    const size_t need_hb = hb_off + (size_t)n * IN_DIM * sizeof(unsigned short);
    const bool use_hb = (ws_size >= need_hb);
    if (!use_hb) hb = nullptr;

    // packed edges live in the tail of d_out; fully consumed by buildC before
    // agg overwrites d_out, fully rewritten every call (replay-safe).
    int* packed = (int*)d_out + (out_size - E);

    hipMemsetAsync(bhist, 0, 1024 * sizeof(int), stream);

    packW_kernel<<<16, 256, 0, stream>>>(W, pw);
    if (use_hb) prep_kernel<<<(n * IN_DIM / 8 + 255) / 256, 256, 0, stream>>>(h, hb, n * IN_DIM / 8);
    hist_kernel<<<256, 256, 0, stream>>>(dst, bhist, E, nbuk);
    bscan_kernel<<<1, 256, 0, stream>>>(bhist, boff, bcur, nbuk, E);

    const int NB = 256;
    const int chunk = (E + NB - 1) / NB;  // 6250
    scatterB_kernel<<<NB, 256, 0, stream>>>(src, dst, bcur, packed, E, chunk);

    buildC_kernel<<<nbuk, 256, 0, stream>>>(packed, boff, sorted_src, rowptr, norm, n);

    agg_kernel<<<(n + 3) / 4, 256, 0, stream>>>(h, hb, norm, rowptr, sorted_src, out, n, E);

    gemm_kernel<<<(n + 63) / 64, 256, 0, stream>>>(h, hb, out, pw, bias, out, n);
}